// Round 1
// baseline (1774.976 us; speedup 1.0000x reference)
//
#include <hip/hip_runtime.h>
#include <math.h>

#define NUM_USERS 100000
#define NUM_ITEMS 50000
#define N_NODES   150000   // NUM_USERS + NUM_ITEMS
#define LATENT    64
#define N_EDGES   2400000
#define BATCH     16384

// ---------------------------------------------------------------------------
// cur = concat(user_emb, item_emb), flat float4 copy
// ---------------------------------------------------------------------------
__global__ void k_concat(const float4* __restrict__ ue,
                         const float4* __restrict__ ie,
                         float4* __restrict__ cur) {
    int i = blockIdx.x * blockDim.x + threadIdx.x;
    const int nU4 = NUM_USERS * (LATENT / 4);   // 1,600,000
    const int nT4 = N_NODES   * (LATENT / 4);   // 2,400,000
    if (i < nU4)       cur[i] = ue[i];
    else if (i < nT4)  cur[i] = ie[i - nU4];
}

// ---------------------------------------------------------------------------
// vsel[b, 0:64]  = user_emb[users[b]]   (layer-0 contribution)
// vsel[b,64:128] = item_emb[items[b]]
// ---------------------------------------------------------------------------
__global__ void k_sel_init(const int* __restrict__ users,
                           const int* __restrict__ items,
                           const float* __restrict__ ue,
                           const float* __restrict__ ie,
                           float* __restrict__ vsel) {
    int t = blockIdx.x * blockDim.x + threadIdx.x;   // BATCH*64 threads
    int b = t >> 6, d = t & 63;
    vsel[b * 128 + d]      = ue[users[b] * 64 + d];
    vsel[b * 128 + 64 + d] = ie[items[b] * 64 + d];
}

// ---------------------------------------------------------------------------
// SpMM scatter: one wave per edge, lane = latent dim.
// nxt[rows[e], :] += vals[e] * cur[cols[e], :]
// ---------------------------------------------------------------------------
__global__ void k_spmm(const int* __restrict__ rows,
                       const int* __restrict__ cols,
                       const float* __restrict__ vals,
                       const float* __restrict__ cur,
                       float* __restrict__ nxt) {
    unsigned int g = blockIdx.x * blockDim.x + threadIdx.x;
    int e    = (int)(g >> 6);
    int lane = threadIdx.x & 63;
    if (e < N_EDGES) {
        int   r = rows[e];
        int   c = cols[e];
        float v = vals[e];
        float x = cur[c * 64 + lane];
        atomicAdd(&nxt[r * 64 + lane], v * x);
    }
}

// ---------------------------------------------------------------------------
// vsel[b, 0:64]  += src[users[b]]
// vsel[b,64:128] += src[NUM_USERS + items[b]]
// ---------------------------------------------------------------------------
__global__ void k_gather_add(const int* __restrict__ users,
                             const int* __restrict__ items,
                             const float* __restrict__ src,
                             float* __restrict__ vsel) {
    int t = blockIdx.x * blockDim.x + threadIdx.x;
    int b = t >> 6, d = t & 63;
    vsel[b * 128 + d]      += src[users[b] * 64 + d];
    vsel[b * 128 + 64 + d] += src[(NUM_USERS + items[b]) * 64 + d];
}

// ---------------------------------------------------------------------------
// MLP head: v = vsel/4 (128) -> relu(@W0+b0) (64) -> relu(@W1+b1) (32)
//           -> @Wa+ba (1) -> sigmoid.  One wave per batch row.
// ---------------------------------------------------------------------------
__global__ __launch_bounds__(256) void k_mlp(const float* __restrict__ vsel,
                                             const float* __restrict__ W0,
                                             const float* __restrict__ b0,
                                             const float* __restrict__ W1,
                                             const float* __restrict__ b1,
                                             const float* __restrict__ Wa,
                                             const float* __restrict__ ba,
                                             float* __restrict__ out) {
    __shared__ float sW0[128 * 64];
    __shared__ float sW1[64 * 32];
    __shared__ float sWa[32];
    __shared__ float sb0[64];
    __shared__ float sb1[32];

    for (int i = threadIdx.x; i < 128 * 64; i += 256) sW0[i] = W0[i];
    for (int i = threadIdx.x; i < 64 * 32;  i += 256) sW1[i] = W1[i];
    if (threadIdx.x < 32) sWa[threadIdx.x] = Wa[threadIdx.x];
    if (threadIdx.x < 64) sb0[threadIdx.x] = b0[threadIdx.x];
    if (threadIdx.x >= 64 && threadIdx.x < 96) sb1[threadIdx.x - 64] = b1[threadIdx.x - 64];
    float sba = ba[0];
    __syncthreads();

    int lane   = threadIdx.x & 63;
    int wave   = blockIdx.x * (blockDim.x >> 6) + (threadIdx.x >> 6);
    int nwaves = gridDim.x * (blockDim.x >> 6);

    for (int b = wave; b < BATCH; b += nwaves) {
        float vlo = vsel[b * 128 + lane]      * 0.25f;
        float vhi = vsel[b * 128 + 64 + lane] * 0.25f;

        // h0[lane] = relu( sum_k v[k] * W0[k,lane] + b0[lane] )
        float h0 = 0.f;
        #pragma unroll
        for (int k = 0; k < 64; k++) {
            float a = __shfl(vlo, k);
            h0 = fmaf(a, sW0[k * 64 + lane], h0);
        }
        #pragma unroll
        for (int k = 0; k < 64; k++) {
            float a = __shfl(vhi, k);
            h0 = fmaf(a, sW0[(64 + k) * 64 + lane], h0);
        }
        h0 = fmaxf(h0 + sb0[lane], 0.f);

        // h1[lane<32] = relu( sum_k h0[k] * W1[k,lane] + b1[lane] )
        float h1 = 0.f;
        #pragma unroll
        for (int k = 0; k < 64; k++) {
            float a = __shfl(h0, k);
            if (lane < 32) h1 = fmaf(a, sW1[k * 32 + lane], h1);
        }
        float contrib = 0.f;
        if (lane < 32) {
            h1 = fmaxf(h1 + sb1[lane], 0.f);
            contrib = h1 * sWa[lane];
        }
        // reduce over 64 lanes (upper 32 contribute 0)
        #pragma unroll
        for (int off = 32; off > 0; off >>= 1)
            contrib += __shfl_down(contrib, off);

        if (lane == 0) {
            float logit = contrib + sba;
            out[b] = 1.0f / (1.0f + expf(-logit));
        }
    }
}

// ---------------------------------------------------------------------------
extern "C" void kernel_launch(void* const* d_in, const int* in_sizes, int n_in,
                              void* d_out, int out_size, void* d_ws, size_t ws_size,
                              hipStream_t stream) {
    const int*   users = (const int*)  d_in[0];
    const int*   items = (const int*)  d_in[1];
    const int*   rows  = (const int*)  d_in[2];
    const int*   cols  = (const int*)  d_in[3];
    const float* vals  = (const float*)d_in[4];
    const float* ue    = (const float*)d_in[5];
    const float* ie    = (const float*)d_in[6];
    const float* W0    = (const float*)d_in[7];
    const float* b0    = (const float*)d_in[8];
    const float* W1    = (const float*)d_in[9];
    const float* b1    = (const float*)d_in[10];
    const float* Wa    = (const float*)d_in[11];
    const float* ba    = (const float*)d_in[12];
    float* out = (float*)d_out;

    const size_t nodeElems = (size_t)N_NODES * LATENT;       // 9.6 M floats
    float* bufA = (float*)d_ws;
    float* bufB = bufA + nodeElems;
    float* vsel = bufB + nodeElems;                          // BATCH*128 floats

    // cur = concat(embeddings)
    k_concat<<<(N_NODES * (LATENT / 4) + 255) / 256, 256, 0, stream>>>(
        (const float4*)ue, (const float4*)ie, (float4*)bufA);
    // vsel = layer-0 selected rows
    k_sel_init<<<(BATCH * 64) / 256, 256, 0, stream>>>(users, items, ue, ie, vsel);

    const int spmmGrid = (N_EDGES * 64) / 256;   // 600,000 blocks
    const int gGrid    = (BATCH * 64) / 256;

    // layer 1: A -> B
    hipMemsetAsync(bufB, 0, nodeElems * sizeof(float), stream);
    k_spmm<<<spmmGrid, 256, 0, stream>>>(rows, cols, vals, bufA, bufB);
    k_gather_add<<<gGrid, 256, 0, stream>>>(users, items, bufB, vsel);

    // layer 2: B -> A
    hipMemsetAsync(bufA, 0, nodeElems * sizeof(float), stream);
    k_spmm<<<spmmGrid, 256, 0, stream>>>(rows, cols, vals, bufB, bufA);
    k_gather_add<<<gGrid, 256, 0, stream>>>(users, items, bufA, vsel);

    // layer 3: A -> B
    hipMemsetAsync(bufB, 0, nodeElems * sizeof(float), stream);
    k_spmm<<<spmmGrid, 256, 0, stream>>>(rows, cols, vals, bufA, bufB);
    k_gather_add<<<gGrid, 256, 0, stream>>>(users, items, bufB, vsel);

    // MLP head
    k_mlp<<<1024, 256, 0, stream>>>(vsel, W0, b0, W1, b1, Wa, ba, out);
}

// Round 2
// 923.903 us; speedup vs baseline: 1.9212x; 1.9212x over previous
//
#include <hip/hip_runtime.h>
#include <math.h>

#define NUM_USERS 100000
#define NUM_ITEMS 50000
#define N_NODES   150000   // NUM_USERS + NUM_ITEMS
#define LATENT    64
#define N_EDGES   2400000
#define BATCH     16384
#define SCAN_BLK  1024
#define SCAN_GRID ((N_NODES + SCAN_BLK - 1) / SCAN_BLK)   // 147

// ---------------------------------------------------------------------------
// cur = concat(user_emb, item_emb), flat float4 copy
// ---------------------------------------------------------------------------
__global__ void k_concat(const float4* __restrict__ ue,
                         const float4* __restrict__ ie,
                         float4* __restrict__ cur) {
    int i = blockIdx.x * blockDim.x + threadIdx.x;
    const int nU4 = NUM_USERS * (LATENT / 4);
    const int nT4 = N_NODES   * (LATENT / 4);
    if (i < nU4)       cur[i] = ue[i];
    else if (i < nT4)  cur[i] = ie[i - nU4];
}

// ---------------------------------------------------------------------------
// vsel[b, 0:64]  = user_emb[users[b]]   (layer-0 contribution)
// vsel[b,64:128] = item_emb[items[b]]
// ---------------------------------------------------------------------------
__global__ void k_sel_init(const int* __restrict__ users,
                           const int* __restrict__ items,
                           const float* __restrict__ ue,
                           const float* __restrict__ ie,
                           float* __restrict__ vsel) {
    int t = blockIdx.x * blockDim.x + threadIdx.x;
    int b = t >> 6, d = t & 63;
    vsel[b * 128 + d]      = ue[users[b] * 64 + d];
    vsel[b * 128 + 64 + d] = ie[items[b] * 64 + d];
}

// ---------------------------------------------------------------------------
// CSR build step 1: histogram of row degrees
// ---------------------------------------------------------------------------
__global__ void k_hist(const int* __restrict__ rows, int* __restrict__ counts) {
    int e = blockIdx.x * blockDim.x + threadIdx.x;
    if (e < N_EDGES) atomicAdd(&counts[rows[e]], 1);
}

// ---------------------------------------------------------------------------
// CSR build step 2: exclusive scan (3-phase)
// ---------------------------------------------------------------------------
__global__ __launch_bounds__(SCAN_BLK) void k_scan_a(const int* __restrict__ counts,
                                                     int* __restrict__ startArr,
                                                     int* __restrict__ bsum) {
    __shared__ int sh[SCAN_BLK];
    int i = blockIdx.x * SCAN_BLK + threadIdx.x;
    int v = (i < N_NODES) ? counts[i] : 0;
    sh[threadIdx.x] = v;
    __syncthreads();
    for (int off = 1; off < SCAN_BLK; off <<= 1) {
        int t = (threadIdx.x >= off) ? sh[threadIdx.x - off] : 0;
        __syncthreads();
        sh[threadIdx.x] += t;
        __syncthreads();
    }
    if (i < N_NODES) startArr[i] = sh[threadIdx.x] - v;           // exclusive
    if (threadIdx.x == SCAN_BLK - 1) bsum[blockIdx.x] = sh[threadIdx.x];
}

__global__ __launch_bounds__(256) void k_scan_b(int* __restrict__ bsum, int n) {
    __shared__ int sh[256];
    int v = (threadIdx.x < n) ? bsum[threadIdx.x] : 0;
    sh[threadIdx.x] = v;
    __syncthreads();
    for (int off = 1; off < 256; off <<= 1) {
        int t = (threadIdx.x >= off) ? sh[threadIdx.x - off] : 0;
        __syncthreads();
        sh[threadIdx.x] += t;
        __syncthreads();
    }
    if (threadIdx.x < n) bsum[threadIdx.x] = sh[threadIdx.x] - v; // exclusive
}

__global__ __launch_bounds__(SCAN_BLK) void k_scan_c(int* __restrict__ startArr,
                                                     const int* __restrict__ bsum) {
    int i = blockIdx.x * SCAN_BLK + threadIdx.x;
    if (i < N_NODES) startArr[i] += bsum[blockIdx.x];
}

// ---------------------------------------------------------------------------
// CSR build step 3: fill (col,val) buckets
// ---------------------------------------------------------------------------
__global__ void k_fill(const int* __restrict__ rows, const int* __restrict__ cols,
                       const float* __restrict__ vals,
                       const int* __restrict__ startArr, int* __restrict__ cnt2,
                       int2* __restrict__ edges) {
    int e = blockIdx.x * blockDim.x + threadIdx.x;
    if (e < N_EDGES) {
        int r = rows[e];
        int p = startArr[r] + atomicAdd(&cnt2[r], 1);
        edges[p] = make_int2(cols[e], __float_as_int(vals[e]));
    }
}

// ---------------------------------------------------------------------------
// Gather SpMM: one wave per row, lane = latent dim. Writes EVERY row (so no
// inter-layer memset needed), single 256B store per row, zero float atomics.
// ---------------------------------------------------------------------------
__global__ __launch_bounds__(256) void k_spmm_csr(const int* __restrict__ startArr,
                                                  const int* __restrict__ counts,
                                                  const int2* __restrict__ edges,
                                                  const float* __restrict__ cur,
                                                  float* __restrict__ nxt) {
    int wave = blockIdx.x * 4 + (threadIdx.x >> 6);
    int lane = threadIdx.x & 63;
    if (wave >= N_NODES) return;
    int s = startArr[wave];
    int n = counts[wave];
    float acc = 0.f;
    for (int j = 0; j < n; j++) {
        int2 e = edges[s + j];
        acc = fmaf(__int_as_float(e.y), cur[(size_t)e.x * 64 + lane], acc);
    }
    nxt[(size_t)wave * 64 + lane] = acc;
}

// ---------------------------------------------------------------------------
// Fused layer-3: compute ONLY the 2*BATCH selected rows, add into vsel.
// ---------------------------------------------------------------------------
__global__ __launch_bounds__(256) void k_spmm_sel(const int* __restrict__ users,
                                                  const int* __restrict__ items,
                                                  const int* __restrict__ startArr,
                                                  const int* __restrict__ counts,
                                                  const int2* __restrict__ edges,
                                                  const float* __restrict__ cur,
                                                  float* __restrict__ vsel) {
    int wave = blockIdx.x * 4 + (threadIdx.x >> 6);
    int lane = threadIdx.x & 63;
    int b, row;
    float* dst;
    if (wave < BATCH) {
        b = wave; row = users[b];
        dst = &vsel[b * 128 + lane];
    } else {
        b = wave - BATCH; row = NUM_USERS + items[b];
        dst = &vsel[b * 128 + 64 + lane];
    }
    int s = startArr[row];
    int n = counts[row];
    float acc = 0.f;
    for (int j = 0; j < n; j++) {
        int2 e = edges[s + j];
        acc = fmaf(__int_as_float(e.y), cur[(size_t)e.x * 64 + lane], acc);
    }
    *dst += acc;
}

// ---------------------------------------------------------------------------
// Fallback scatter SpMM (round-1 path, used only if ws_size too small)
// ---------------------------------------------------------------------------
__global__ void k_spmm_atomic(const int* __restrict__ rows,
                              const int* __restrict__ cols,
                              const float* __restrict__ vals,
                              const float* __restrict__ cur,
                              float* __restrict__ nxt) {
    unsigned int g = blockIdx.x * blockDim.x + threadIdx.x;
    int e = (int)(g >> 6);
    int lane = threadIdx.x & 63;
    if (e < N_EDGES) {
        float x = cur[(size_t)cols[e] * 64 + lane];
        atomicAdd(&nxt[(size_t)rows[e] * 64 + lane], vals[e] * x);
    }
}

// ---------------------------------------------------------------------------
// vsel[b, 0:64]  += src[users[b]] ;  vsel[b,64:128] += src[NUM_USERS+items[b]]
// ---------------------------------------------------------------------------
__global__ void k_gather_add(const int* __restrict__ users,
                             const int* __restrict__ items,
                             const float* __restrict__ src,
                             float* __restrict__ vsel) {
    int t = blockIdx.x * blockDim.x + threadIdx.x;
    int b = t >> 6, d = t & 63;
    vsel[b * 128 + d]      += src[users[b] * 64 + d];
    vsel[b * 128 + 64 + d] += src[(size_t)(NUM_USERS + items[b]) * 64 + d];
}

// ---------------------------------------------------------------------------
// MLP head (unchanged): one wave per batch row, weights in LDS.
// ---------------------------------------------------------------------------
__global__ __launch_bounds__(256) void k_mlp(const float* __restrict__ vsel,
                                             const float* __restrict__ W0,
                                             const float* __restrict__ b0,
                                             const float* __restrict__ W1,
                                             const float* __restrict__ b1,
                                             const float* __restrict__ Wa,
                                             const float* __restrict__ ba,
                                             float* __restrict__ out) {
    __shared__ float sW0[128 * 64];
    __shared__ float sW1[64 * 32];
    __shared__ float sWa[32];
    __shared__ float sb0[64];
    __shared__ float sb1[32];

    for (int i = threadIdx.x; i < 128 * 64; i += 256) sW0[i] = W0[i];
    for (int i = threadIdx.x; i < 64 * 32;  i += 256) sW1[i] = W1[i];
    if (threadIdx.x < 32) sWa[threadIdx.x] = Wa[threadIdx.x];
    if (threadIdx.x < 64) sb0[threadIdx.x] = b0[threadIdx.x];
    if (threadIdx.x >= 64 && threadIdx.x < 96) sb1[threadIdx.x - 64] = b1[threadIdx.x - 64];
    float sba = ba[0];
    __syncthreads();

    int lane   = threadIdx.x & 63;
    int wave   = blockIdx.x * (blockDim.x >> 6) + (threadIdx.x >> 6);
    int nwaves = gridDim.x * (blockDim.x >> 6);

    for (int b = wave; b < BATCH; b += nwaves) {
        float vlo = vsel[b * 128 + lane]      * 0.25f;
        float vhi = vsel[b * 128 + 64 + lane] * 0.25f;

        float h0 = 0.f;
        #pragma unroll
        for (int k = 0; k < 64; k++) {
            float a = __shfl(vlo, k);
            h0 = fmaf(a, sW0[k * 64 + lane], h0);
        }
        #pragma unroll
        for (int k = 0; k < 64; k++) {
            float a = __shfl(vhi, k);
            h0 = fmaf(a, sW0[(64 + k) * 64 + lane], h0);
        }
        h0 = fmaxf(h0 + sb0[lane], 0.f);

        float h1 = 0.f;
        #pragma unroll
        for (int k = 0; k < 64; k++) {
            float a = __shfl(h0, k);
            if (lane < 32) h1 = fmaf(a, sW1[k * 32 + lane], h1);
        }
        float contrib = 0.f;
        if (lane < 32) {
            h1 = fmaxf(h1 + sb1[lane], 0.f);
            contrib = h1 * sWa[lane];
        }
        #pragma unroll
        for (int off = 32; off > 0; off >>= 1)
            contrib += __shfl_down(contrib, off);

        if (lane == 0) {
            float logit = contrib + sba;
            out[b] = 1.0f / (1.0f + expf(-logit));
        }
    }
}

// ---------------------------------------------------------------------------
extern "C" void kernel_launch(void* const* d_in, const int* in_sizes, int n_in,
                              void* d_out, int out_size, void* d_ws, size_t ws_size,
                              hipStream_t stream) {
    const int*   users = (const int*)  d_in[0];
    const int*   items = (const int*)  d_in[1];
    const int*   rows  = (const int*)  d_in[2];
    const int*   cols  = (const int*)  d_in[3];
    const float* vals  = (const float*)d_in[4];
    const float* ue    = (const float*)d_in[5];
    const float* ie    = (const float*)d_in[6];
    const float* W0    = (const float*)d_in[7];
    const float* b0    = (const float*)d_in[8];
    const float* W1    = (const float*)d_in[9];
    const float* b1    = (const float*)d_in[10];
    const float* Wa    = (const float*)d_in[11];
    const float* ba    = (const float*)d_in[12];
    float* out = (float*)d_out;

    const size_t nodeElems = (size_t)N_NODES * LATENT;   // 9.6 M floats
    char* ws = (char*)d_ws;
    float* bufA = (float*)ws;                    ws += nodeElems * 4;            // 38.4 MB
    float* bufB = (float*)ws;                    ws += nodeElems * 4;            // 38.4 MB
    float* vsel = (float*)ws;                    ws += (size_t)BATCH * 128 * 4;  // 8.39 MB
    int2*  edges = (int2*)ws;                    ws += (size_t)N_EDGES * 8;      // 19.2 MB
    int* counts   = (int*)ws;                    ws += N_NODES * 4;
    int* startArr = (int*)ws;                    ws += N_NODES * 4;
    int* cnt2     = (int*)ws;                    ws += N_NODES * 4;
    int* bsum     = (int*)ws;                    ws += SCAN_GRID * 4;
    size_t needed = (size_t)(ws - (char*)d_ws);

    const int gGrid = (BATCH * 64) / 256;

    // cur = concat(embeddings); vsel = layer-0 selected rows
    k_concat<<<(N_NODES * (LATENT / 4) + 255) / 256, 256, 0, stream>>>(
        (const float4*)ue, (const float4*)ie, (float4*)bufA);
    k_sel_init<<<gGrid, 256, 0, stream>>>(users, items, ue, ie, vsel);

    if (ws_size >= needed) {
        // ---- CSR build (amortized over 3 layers) ----
        hipMemsetAsync(counts, 0, N_NODES * 4, stream);
        hipMemsetAsync(cnt2,   0, N_NODES * 4, stream);
        k_hist<<<(N_EDGES + 255) / 256, 256, 0, stream>>>(rows, counts);
        k_scan_a<<<SCAN_GRID, SCAN_BLK, 0, stream>>>(counts, startArr, bsum);
        k_scan_b<<<1, 256, 0, stream>>>(bsum, SCAN_GRID);
        k_scan_c<<<SCAN_GRID, SCAN_BLK, 0, stream>>>(startArr, bsum);
        k_fill<<<(N_EDGES + 255) / 256, 256, 0, stream>>>(rows, cols, vals,
                                                          startArr, cnt2, edges);

        // layer 1: A -> B (writes all rows; no memset needed)
        k_spmm_csr<<<N_NODES / 4, 256, 0, stream>>>(startArr, counts, edges, bufA, bufB);
        k_gather_add<<<gGrid, 256, 0, stream>>>(users, items, bufB, vsel);

        // layer 2: B -> A
        k_spmm_csr<<<N_NODES / 4, 256, 0, stream>>>(startArr, counts, edges, bufB, bufA);
        k_gather_add<<<gGrid, 256, 0, stream>>>(users, items, bufA, vsel);

        // layer 3: only the selected rows, fused into vsel
        k_spmm_sel<<<(2 * BATCH) / 4, 256, 0, stream>>>(users, items, startArr,
                                                        counts, edges, bufA, vsel);
    } else {
        // ---- fallback: round-1 atomic scatter path ----
        const int spmmGrid = (N_EDGES * 64) / 256;
        hipMemsetAsync(bufB, 0, nodeElems * 4, stream);
        k_spmm_atomic<<<spmmGrid, 256, 0, stream>>>(rows, cols, vals, bufA, bufB);
        k_gather_add<<<gGrid, 256, 0, stream>>>(users, items, bufB, vsel);
        hipMemsetAsync(bufA, 0, nodeElems * 4, stream);
        k_spmm_atomic<<<spmmGrid, 256, 0, stream>>>(rows, cols, vals, bufB, bufA);
        k_gather_add<<<gGrid, 256, 0, stream>>>(users, items, bufA, vsel);
        hipMemsetAsync(bufB, 0, nodeElems * 4, stream);
        k_spmm_atomic<<<spmmGrid, 256, 0, stream>>>(rows, cols, vals, bufA, bufB);
        k_gather_add<<<gGrid, 256, 0, stream>>>(users, items, bufB, vsel);
    }

    // MLP head
    k_mlp<<<1024, 256, 0, stream>>>(vsel, W0, b0, W1, b1, Wa, ba, out);
}

// Round 3
// 592.307 us; speedup vs baseline: 2.9967x; 1.5598x over previous
//
#include <hip/hip_runtime.h>
#include <math.h>

#define NUM_USERS 100000
#define NUM_ITEMS 50000
#define N_NODES   150000   // NUM_USERS + NUM_ITEMS
#define LATENT    64
#define N_EDGES   2400000
#define BATCH     16384
#define SCAN_BLK  1024
#define SCAN_GRID ((N_NODES + SCAN_BLK - 1) / SCAN_BLK)   // 147

// bf16 helpers (values are small/finite; RNE, no NaN handling needed)
__device__ __forceinline__ unsigned short f2bf(float f) {
    unsigned u = __float_as_uint(f);
    u = (u + 0x7FFF + ((u >> 16) & 1)) >> 16;   // round-to-nearest-even
    return (unsigned short)u;
}
__device__ __forceinline__ float bf2f(unsigned short h) {
    return __uint_as_float(((unsigned)h) << 16);
}

// ---------------------------------------------------------------------------
// table = bf16(concat(user_emb, item_emb)); thread handles 4 elems
// ---------------------------------------------------------------------------
__global__ void k_concat_bf16(const float4* __restrict__ ue,
                              const float4* __restrict__ ie,
                              ushort4* __restrict__ cur) {
    int i = blockIdx.x * blockDim.x + threadIdx.x;
    const int nU4 = NUM_USERS * (LATENT / 4);
    const int nT4 = N_NODES   * (LATENT / 4);
    if (i >= nT4) return;
    float4 v = (i < nU4) ? ue[i] : ie[i - nU4];
    ushort4 o;
    o.x = f2bf(v.x); o.y = f2bf(v.y); o.z = f2bf(v.z); o.w = f2bf(v.w);
    cur[i] = o;
}

// ---------------------------------------------------------------------------
// vsel[b, 0:64]  = user_emb[users[b]]   (layer-0, kept fp32)
// vsel[b,64:128] = item_emb[items[b]]
// ---------------------------------------------------------------------------
__global__ void k_sel_init(const int* __restrict__ users,
                           const int* __restrict__ items,
                           const float* __restrict__ ue,
                           const float* __restrict__ ie,
                           float* __restrict__ vsel) {
    int t = blockIdx.x * blockDim.x + threadIdx.x;
    int b = t >> 6, d = t & 63;
    vsel[b * 128 + d]      = ue[users[b] * 64 + d];
    vsel[b * 128 + 64 + d] = ie[items[b] * 64 + d];
}

// ---------------------------------------------------------------------------
// CSR build
// ---------------------------------------------------------------------------
__global__ void k_hist(const int* __restrict__ rows, int* __restrict__ counts) {
    int e = blockIdx.x * blockDim.x + threadIdx.x;
    if (e < N_EDGES) atomicAdd(&counts[rows[e]], 1);
}

__global__ __launch_bounds__(SCAN_BLK) void k_scan_a(const int* __restrict__ counts,
                                                     int* __restrict__ startArr,
                                                     int* __restrict__ bsum) {
    __shared__ int sh[SCAN_BLK];
    int i = blockIdx.x * SCAN_BLK + threadIdx.x;
    int v = (i < N_NODES) ? counts[i] : 0;
    sh[threadIdx.x] = v;
    __syncthreads();
    for (int off = 1; off < SCAN_BLK; off <<= 1) {
        int t = (threadIdx.x >= off) ? sh[threadIdx.x - off] : 0;
        __syncthreads();
        sh[threadIdx.x] += t;
        __syncthreads();
    }
    if (i < N_NODES) startArr[i] = sh[threadIdx.x] - v;           // exclusive
    if (threadIdx.x == SCAN_BLK - 1) bsum[blockIdx.x] = sh[threadIdx.x];
}

__global__ __launch_bounds__(256) void k_scan_b(int* __restrict__ bsum, int n) {
    __shared__ int sh[256];
    int v = (threadIdx.x < n) ? bsum[threadIdx.x] : 0;
    sh[threadIdx.x] = v;
    __syncthreads();
    for (int off = 1; off < 256; off <<= 1) {
        int t = (threadIdx.x >= off) ? sh[threadIdx.x - off] : 0;
        __syncthreads();
        sh[threadIdx.x] += t;
        __syncthreads();
    }
    if (threadIdx.x < n) bsum[threadIdx.x] = sh[threadIdx.x] - v; // exclusive
}

__global__ __launch_bounds__(SCAN_BLK) void k_scan_c(int* __restrict__ startArr,
                                                     const int* __restrict__ bsum) {
    int i = blockIdx.x * SCAN_BLK + threadIdx.x;
    if (i < N_NODES) startArr[i] += bsum[blockIdx.x];
}

__global__ void k_fill(const int* __restrict__ rows, const int* __restrict__ cols,
                       const float* __restrict__ vals,
                       const int* __restrict__ startArr, int* __restrict__ cnt2,
                       int2* __restrict__ edges) {
    int e = blockIdx.x * blockDim.x + threadIdx.x;
    if (e < N_EDGES) {
        int r = rows[e];
        int p = startArr[r] + atomicAdd(&cnt2[r], 1);
        edges[p] = make_int2(cols[e], __float_as_int(vals[e]));
    }
}

// ---------------------------------------------------------------------------
// Gather SpMM (bf16 table): one wave per row, lane = latent dim.
// Unroll-by-4 keeps 4 gathers in flight; edge descriptors come over the
// scalar pipe (row/start/count are wave-uniform via readfirstlane).
// ---------------------------------------------------------------------------
__global__ __launch_bounds__(256) void k_spmm_csr(const int* __restrict__ startArr,
                                                  const int* __restrict__ counts,
                                                  const int2* __restrict__ edges,
                                                  const unsigned short* __restrict__ cur,
                                                  unsigned short* __restrict__ nxt) {
    int row  = blockIdx.x * 4 + (threadIdx.x >> 6);
    int lane = threadIdx.x & 63;
    if (row >= N_NODES) return;
    row = __builtin_amdgcn_readfirstlane(row);
    int s = __builtin_amdgcn_readfirstlane(startArr[row]);
    int n = __builtin_amdgcn_readfirstlane(counts[row]);
    float acc = 0.f;
    int j = 0;
    for (; j + 4 <= n; j += 4) {
        int2 e0 = edges[s + j + 0];
        int2 e1 = edges[s + j + 1];
        int2 e2 = edges[s + j + 2];
        int2 e3 = edges[s + j + 3];
        float x0 = bf2f(cur[(size_t)e0.x * 64 + lane]);
        float x1 = bf2f(cur[(size_t)e1.x * 64 + lane]);
        float x2 = bf2f(cur[(size_t)e2.x * 64 + lane]);
        float x3 = bf2f(cur[(size_t)e3.x * 64 + lane]);
        acc = fmaf(__int_as_float(e0.y), x0, acc);
        acc = fmaf(__int_as_float(e1.y), x1, acc);
        acc = fmaf(__int_as_float(e2.y), x2, acc);
        acc = fmaf(__int_as_float(e3.y), x3, acc);
    }
    for (; j < n; j++) {
        int2 e = edges[s + j];
        acc = fmaf(__int_as_float(e.y), bf2f(cur[(size_t)e.x * 64 + lane]), acc);
    }
    nxt[(size_t)row * 64 + lane] = f2bf(acc);
}

// ---------------------------------------------------------------------------
// Fused layer-3 + layer-2 gather_add: for each selected row,
// vsel += cur[row] (layer-2 value) + SpMM(cur)[row] (layer-3 value).
// ---------------------------------------------------------------------------
__global__ __launch_bounds__(256) void k_spmm_sel(const int* __restrict__ users,
                                                  const int* __restrict__ items,
                                                  const int* __restrict__ startArr,
                                                  const int* __restrict__ counts,
                                                  const int2* __restrict__ edges,
                                                  const unsigned short* __restrict__ cur,
                                                  float* __restrict__ vsel) {
    int wave = blockIdx.x * 4 + (threadIdx.x >> 6);
    int lane = threadIdx.x & 63;
    int b, row;
    float* dst;
    if (wave < BATCH) {
        b = wave; row = users[b];
        dst = &vsel[b * 128 + lane];
    } else {
        b = wave - BATCH; row = NUM_USERS + items[b];
        dst = &vsel[b * 128 + 64 + lane];
    }
    int s = startArr[row];
    int n = counts[row];
    float acc = bf2f(cur[(size_t)row * 64 + lane]);   // layer-2 contribution
    int j = 0;
    for (; j + 4 <= n; j += 4) {
        int2 e0 = edges[s + j + 0];
        int2 e1 = edges[s + j + 1];
        int2 e2 = edges[s + j + 2];
        int2 e3 = edges[s + j + 3];
        float x0 = bf2f(cur[(size_t)e0.x * 64 + lane]);
        float x1 = bf2f(cur[(size_t)e1.x * 64 + lane]);
        float x2 = bf2f(cur[(size_t)e2.x * 64 + lane]);
        float x3 = bf2f(cur[(size_t)e3.x * 64 + lane]);
        acc = fmaf(__int_as_float(e0.y), x0, acc);
        acc = fmaf(__int_as_float(e1.y), x1, acc);
        acc = fmaf(__int_as_float(e2.y), x2, acc);
        acc = fmaf(__int_as_float(e3.y), x3, acc);
    }
    for (; j < n; j++) {
        int2 e = edges[s + j];
        acc = fmaf(__int_as_float(e.y), bf2f(cur[(size_t)e.x * 64 + lane]), acc);
    }
    *dst += acc;
}

// ---------------------------------------------------------------------------
// vsel += bf16 src at selected rows (used after layer 1 only)
// ---------------------------------------------------------------------------
__global__ void k_gather_add(const int* __restrict__ users,
                             const int* __restrict__ items,
                             const unsigned short* __restrict__ src,
                             float* __restrict__ vsel) {
    int t = blockIdx.x * blockDim.x + threadIdx.x;
    int b = t >> 6, d = t & 63;
    vsel[b * 128 + d]      += bf2f(src[(size_t)users[b] * 64 + d]);
    vsel[b * 128 + 64 + d] += bf2f(src[(size_t)(NUM_USERS + items[b]) * 64 + d]);
}

// ---------------------------------------------------------------------------
// MLP head: one wave per batch row, weights in LDS.
// ---------------------------------------------------------------------------
__global__ __launch_bounds__(256) void k_mlp(const float* __restrict__ vsel,
                                             const float* __restrict__ W0,
                                             const float* __restrict__ b0,
                                             const float* __restrict__ W1,
                                             const float* __restrict__ b1,
                                             const float* __restrict__ Wa,
                                             const float* __restrict__ ba,
                                             float* __restrict__ out) {
    __shared__ float sW0[128 * 64];
    __shared__ float sW1[64 * 32];
    __shared__ float sWa[32];
    __shared__ float sb0[64];
    __shared__ float sb1[32];

    for (int i = threadIdx.x; i < 128 * 64; i += 256) sW0[i] = W0[i];
    for (int i = threadIdx.x; i < 64 * 32;  i += 256) sW1[i] = W1[i];
    if (threadIdx.x < 32) sWa[threadIdx.x] = Wa[threadIdx.x];
    if (threadIdx.x < 64) sb0[threadIdx.x] = b0[threadIdx.x];
    if (threadIdx.x >= 64 && threadIdx.x < 96) sb1[threadIdx.x - 64] = b1[threadIdx.x - 64];
    float sba = ba[0];
    __syncthreads();

    int lane   = threadIdx.x & 63;
    int wave   = blockIdx.x * (blockDim.x >> 6) + (threadIdx.x >> 6);
    int nwaves = gridDim.x * (blockDim.x >> 6);

    for (int b = wave; b < BATCH; b += nwaves) {
        float vlo = vsel[b * 128 + lane]      * 0.25f;
        float vhi = vsel[b * 128 + 64 + lane] * 0.25f;

        float h0 = 0.f;
        #pragma unroll
        for (int k = 0; k < 64; k++) {
            float a = __shfl(vlo, k);
            h0 = fmaf(a, sW0[k * 64 + lane], h0);
        }
        #pragma unroll
        for (int k = 0; k < 64; k++) {
            float a = __shfl(vhi, k);
            h0 = fmaf(a, sW0[(64 + k) * 64 + lane], h0);
        }
        h0 = fmaxf(h0 + sb0[lane], 0.f);

        float h1 = 0.f;
        #pragma unroll
        for (int k = 0; k < 64; k++) {
            float a = __shfl(h0, k);
            if (lane < 32) h1 = fmaf(a, sW1[k * 32 + lane], h1);
        }
        float contrib = 0.f;
        if (lane < 32) {
            h1 = fmaxf(h1 + sb1[lane], 0.f);
            contrib = h1 * sWa[lane];
        }
        #pragma unroll
        for (int off = 32; off > 0; off >>= 1)
            contrib += __shfl_down(contrib, off);

        if (lane == 0) {
            float logit = contrib + sba;
            out[b] = 1.0f / (1.0f + expf(-logit));
        }
    }
}

// ---------------------------------------------------------------------------
extern "C" void kernel_launch(void* const* d_in, const int* in_sizes, int n_in,
                              void* d_out, int out_size, void* d_ws, size_t ws_size,
                              hipStream_t stream) {
    const int*   users = (const int*)  d_in[0];
    const int*   items = (const int*)  d_in[1];
    const int*   rows  = (const int*)  d_in[2];
    const int*   cols  = (const int*)  d_in[3];
    const float* vals  = (const float*)d_in[4];
    const float* ue    = (const float*)d_in[5];
    const float* ie    = (const float*)d_in[6];
    const float* W0    = (const float*)d_in[7];
    const float* b0    = (const float*)d_in[8];
    const float* W1    = (const float*)d_in[9];
    const float* b1    = (const float*)d_in[10];
    const float* Wa    = (const float*)d_in[11];
    const float* ba    = (const float*)d_in[12];
    float* out = (float*)d_out;

    const size_t nodeElems = (size_t)N_NODES * LATENT;   // 9.6 M
    char* ws = (char*)d_ws;
    unsigned short* tabA = (unsigned short*)ws;  ws += nodeElems * 2;            // 19.2 MB
    unsigned short* tabB = (unsigned short*)ws;  ws += nodeElems * 2;            // 19.2 MB
    float* vsel = (float*)ws;                    ws += (size_t)BATCH * 128 * 4;  // 8.39 MB
    int2*  edges = (int2*)ws;                    ws += (size_t)N_EDGES * 8;      // 19.2 MB
    int* counts   = (int*)ws;                    ws += N_NODES * 4;
    int* startArr = (int*)ws;                    ws += N_NODES * 4;
    int* cnt2     = (int*)ws;                    ws += N_NODES * 4;
    int* bsum     = (int*)ws;                    ws += SCAN_GRID * 4;

    const int gGrid = (BATCH * 64) / 256;

    // bf16 table + fp32 layer-0 selection
    k_concat_bf16<<<(N_NODES * (LATENT / 4) + 255) / 256, 256, 0, stream>>>(
        (const float4*)ue, (const float4*)ie, (ushort4*)tabA);
    k_sel_init<<<gGrid, 256, 0, stream>>>(users, items, ue, ie, vsel);

    // ---- CSR build (amortized over 3 layers) ----
    hipMemsetAsync(counts, 0, N_NODES * 4, stream);
    hipMemsetAsync(cnt2,   0, N_NODES * 4, stream);
    k_hist<<<(N_EDGES + 255) / 256, 256, 0, stream>>>(rows, counts);
    k_scan_a<<<SCAN_GRID, SCAN_BLK, 0, stream>>>(counts, startArr, bsum);
    k_scan_b<<<1, 256, 0, stream>>>(bsum, SCAN_GRID);
    k_scan_c<<<SCAN_GRID, SCAN_BLK, 0, stream>>>(startArr, bsum);
    k_fill<<<(N_EDGES + 255) / 256, 256, 0, stream>>>(rows, cols, vals,
                                                      startArr, cnt2, edges);

    // layer 1: A -> B (writes every row; no memset needed)
    k_spmm_csr<<<(N_NODES + 3) / 4, 256, 0, stream>>>(startArr, counts, edges, tabA, tabB);
    k_gather_add<<<gGrid, 256, 0, stream>>>(users, items, tabB, vsel);

    // layer 2: B -> A
    k_spmm_csr<<<(N_NODES + 3) / 4, 256, 0, stream>>>(startArr, counts, edges, tabB, tabA);

    // layer 3 (selected rows only) fused with layer-2 gather_add
    k_spmm_sel<<<(2 * BATCH) / 4, 256, 0, stream>>>(users, items, startArr,
                                                    counts, edges, tabA, vsel);

    // MLP head
    k_mlp<<<1024, 256, 0, stream>>>(vsel, W0, b0, W1, b1, Wa, ba, out);
}